// Round 8
// baseline (558.873 us; speedup 1.0000x reference)
//
#include <hip/hip_runtime.h>
#include <hip/hip_bf16.h>

#define N_ATOMS 10000
#define N_PAIRS 320000
#define C_ 64
#define NB_ 10

typedef short bf16x8 __attribute__((ext_vector_type(8)));
typedef float f32x4 __attribute__((ext_vector_type(4)));

__device__ __forceinline__ float bf2f(__hip_bfloat16 x) { return __bfloat162float(x); }
__device__ __forceinline__ float ldf(const void* p, int i, int isf32) {
    return isf32 ? ((const float*)p)[i] : bf2f(((const __hip_bfloat16*)p)[i]);
}
__device__ __forceinline__ short f2bs(float x) {
    __hip_bfloat16 h = __float2bfloat16(x);
    return *reinterpret_cast<short*>(&h);
}
__device__ __forceinline__ float bs2f(unsigned short s) {
    return __uint_as_float(((unsigned)s) << 16);
}
// fast tanh: 1 - 2/(exp(2x)+1). err ~1e-6, saturates correctly at +-inf.
__device__ __forceinline__ float tanh_fast(float x) {
    const float e = __expf(2.0f * x);
    return 1.0f - 2.0f * __builtin_amdgcn_rcpf(e + 1.0f);
}

// wbuf f32 offsets
#define W_PPREW1 0
#define W_PPREB1 4096
#define W_PPREW2 4160
#define W_PPREB2 8256
#define W_PIW    8320
#define W_PIB    90240
#define W_IIW    90880
#define W_PPOSTW1 99072
#define W_PPOSTW2 107264
#define W_EQW    111360
#define W_Q1W    115456
#define W_Q1B    123648
#define W_Q2W    123712
#define W_Q2B    131904
#define W_TOTAL  132032

// ---------------- probe dtype ----------------
__global__ void k_probe(const void* __restrict__ d3, int* __restrict__ flag)
{
    if (threadIdx.x == 0 && blockIdx.x == 0) {
        float sf = 0.f, sb = 0.f;
        const float* f = (const float*)d3;
        const __hip_bfloat16* b = (const __hip_bfloat16*)d3;
        for (int r = 0; r < 4; r++) {
            float x = f[r*3], y = f[r*3+1], z = f[r*3+2];
            float n = x*x + y*y + z*z;
            sf += isfinite(n) ? fabsf(n - 1.f) : 1e30f;
            float xb = bf2f(b[r*3]), yb = bf2f(b[r*3+1]), zb = bf2f(b[r*3+2]);
            float nb = xb*xb + yb*yb + zb*zb;
            sb += isfinite(nb) ? fabsf(nb - 1.f) : 1e30f;
        }
        *flag = (sf < sb) ? 1 : 0;
    }
}

// ---------------- gather all weights into f32 wbuf ----------------
__global__ __launch_bounds__(256) void k_convert(
    const void* s0, const void* s1, const void* s2, const void* s3,
    const void* s4, const void* s5, const void* s6, const void* s7,
    const void* s8, const void* s9, const void* s10, const void* s11,
    const void* s12, const void* s13,
    float* __restrict__ wbuf, const int* __restrict__ flagp)
{
    const int idx = blockIdx.x * 256 + threadIdx.x;
    if (idx >= W_TOTAL) return;
    const int isf32 = *flagp;
    const int offs[15] = {W_PPREW1, W_PPREB1, W_PPREW2, W_PPREB2, W_PIW, W_PIB,
                          W_IIW, W_PPOSTW1, W_PPOSTW2, W_EQW, W_Q1W, W_Q1B,
                          W_Q2W, W_Q2B, W_TOTAL};
    const void* srcs[14] = {s0,s1,s2,s3,s4,s5,s6,s7,s8,s9,s10,s11,s12,s13};
    int t = 0;
    while (idx >= offs[t + 1]) t++;
    wbuf[idx] = ldf(srcs[t], idx - offs[t], isf32);
}

// ---------------- pack MFMA B-operand buffers (hi + lo split) ----------------
__global__ __launch_bounds__(256) void k_pack(
    const float* __restrict__ wbuf,
    short* __restrict__ piWBh, short* __restrict__ piWBl,
    short* __restrict__ iiWh, short* __restrict__ iiWl)
{
    int idx = blockIdx.x * 256 + threadIdx.x;
    if (idx < 81920) {
        const int j = idx & 7, lane = (idx >> 3) & 63, s = (idx >> 9) & 3, T = idx >> 11;
        const int k = s * 32 + (lane >> 4) * 8 + j;
        const int colp = T * 16 + (lane & 15);
        const int b = colp >> 6, c = colp & 63;
        const float v = wbuf[W_PIW + k * 640 + c * 10 + b];
        const short hs = f2bs(v);
        piWBh[idx] = hs;
        piWBl[idx] = f2bs(v - bs2f((unsigned short)hs));
        return;
    }
    idx -= 81920;
    if (idx < 8192) {
        const int j = idx & 7, lane = (idx >> 3) & 63, s2 = (idx >> 9) & 1, ct = idx >> 10;
        const int k = s2 * 32 + (lane >> 4) * 8 + j;
        const int col = ct * 16 + (lane & 15);
        const float wv = wbuf[W_IIW + k * 128 + col];
        const short hs = f2bs(wv);
        iiWh[idx] = hs;
        iiWl[idx] = f2bs(wv - bs2f((unsigned short)hs));
    }
}

// ---------------- p1_in split into hi/lo bf16 ----------------
__global__ __launch_bounds__(256) void k_p1in(
    const void* __restrict__ p1, const float* __restrict__ wbuf,
    const int* __restrict__ flagp,
    unsigned short* __restrict__ p1h, unsigned short* __restrict__ p1l)
{
    const float* W1 = wbuf + W_PPREW1;
    const float* b1 = wbuf + W_PPREB1;
    const float* W2 = wbuf + W_PPREW2;
    const float* b2 = wbuf + W_PPREB2;
    const int isf32 = *flagp;
    __shared__ float x[4][C_];
    __shared__ float h[4][C_];
    const int t = threadIdx.x;
    const int slot = t >> 6, c = t & 63;
    const int atom = blockIdx.x * 4 + slot;
    x[slot][c] = ldf(p1, atom * C_ + c, isf32);
    __syncthreads();
    float acc = b1[c];
    for (int k = 0; k < C_; k++) acc += x[slot][k] * W1[k * C_ + c];
    h[slot][c] = tanh_fast(acc);
    __syncthreads();
    acc = b2[c];
    for (int k = 0; k < C_; k++) acc += h[slot][k] * W2[k * C_ + c];
    const float f = tanh_fast(acc);
    const short hs = f2bs(f);
    p1h[atom * C_ + c] = (unsigned short)hs;
    p1l[atom * C_ + c] = (unsigned short)f2bs(f - bs2f((unsigned short)hs));
}

// ---------------- sort machinery ----------------
__global__ __launch_bounds__(256) void k_hist(const int* __restrict__ ind2, int* __restrict__ cnt)
{
    const int p = blockIdx.x * 256 + threadIdx.x;
    if (p < N_PAIRS) atomicAdd(&cnt[ind2[2 * p]], 1);
}
__global__ __launch_bounds__(256) void k_scan(const int* __restrict__ cnt, int* __restrict__ offs)
{
    __shared__ int part[256];
    __shared__ int base[257];
    const int t = threadIdx.x;
    const int lo = t * 40, hi = (lo + 40 < N_ATOMS) ? lo + 40 : N_ATOMS;
    int s = 0;
    for (int b = lo; b < hi; b++) s += cnt[b];
    part[t] = s;
    __syncthreads();
    if (t == 0) {
        int run = 0;
        for (int i = 0; i < 256; i++) { base[i] = run; run += part[i]; }
        base[256] = run;
    }
    __syncthreads();
    int run = base[t];
    for (int b = lo; b < hi; b++) { offs[b] = run; run += cnt[b]; }
    if (t == 0) offs[N_ATOMS] = base[256];
}
__global__ __launch_bounds__(256) void k_cpcur(const int* __restrict__ offs, int* __restrict__ cur)
{
    const int i = blockIdx.x * 256 + threadIdx.x;
    if (i < N_ATOMS) cur[i] = offs[i];
}
__global__ __launch_bounds__(256) void k_scatter(const int* __restrict__ ind2,
                                                 int* __restrict__ cur, int* __restrict__ perm)
{
    const int p = blockIdx.x * 256 + threadIdx.x;
    if (p >= N_PAIRS) return;
    const int pos = atomicAdd(&cur[ind2[2 * p]], 1);
    perm[pos] = p;
}

// ---------------- v = segment_sum(d3*fc) via sorted head-scan ----------------
__global__ __launch_bounds__(256) void k_vscat(
    const int* __restrict__ ind2, const void* __restrict__ d3,
    const void* __restrict__ fc, const int* __restrict__ flagp,
    const int* __restrict__ perm, float* __restrict__ v)
{
    __shared__ int iA[256];
    __shared__ float sx[256], sy[256], sz[256];
    const int t = threadIdx.x;
    const int q = blockIdx.x * 256 + t;
    const int isf32 = *flagp;
    const int p = perm[q];
    const int ia = ind2[2 * p];
    const float f = ldf(fc, p, isf32);
    iA[t] = ia;
    sx[t] = ldf(d3, 3 * p + 0, isf32) * f;
    sy[t] = ldf(d3, 3 * p + 1, isf32) * f;
    sz[t] = ldf(d3, 3 * p + 2, isf32) * f;
    __syncthreads();
    const bool head = (t == 0) || (iA[t - 1] != ia);
    if (head) {
        float ax = sx[t], ay = sy[t], az = sz[t];
        int m = t + 1;
        while (m < 256 && iA[m] == ia) { ax += sx[m]; ay += sy[m]; az += sz[m]; m++; }
        atomicAdd(&v[ia * 3 + 0], ax);
        atomicAdd(&v[ia * 3 + 1], ay);
        atomicAdd(&v[ia * 3 + 2], az);
    }
}

// ---------------- main per-pair MFMA kernel, sorted order, segmented scatter ----------------
// 64 pairs/block in perm (sorted-by-i) order. GEMM1+GEMM2 as before; GEMM2
// output staged in LDS (overlay of Bbuf+preL, exactly 33792 B), then
// in-block segmented reduction -> ~3 distinct i per block -> ~5M atomics total
// (vs 102M un-sorted, and no 160MB ip round-trip).
__global__ __launch_bounds__(256) void k_pairs(
    const int* __restrict__ ind2, const void* __restrict__ basis,
    const void* __restrict__ d3, const void* __restrict__ fc,
    const void* __restrict__ p3,
    const float* __restrict__ wbuf,
    const short* __restrict__ piWBh, const short* __restrict__ piWBl,
    const short* __restrict__ iiWh, const short* __restrict__ iiWl,
    const unsigned short* __restrict__ p1h, const unsigned short* __restrict__ p1l,
    const int* __restrict__ flagp, const float* __restrict__ vglob,
    const int* __restrict__ perm,
    float* __restrict__ p1scat, float* __restrict__ p3acc)
{
    __shared__ __align__(16) char U[33792];   // Bbuf(16K)+preL(17.4K) -> ipL(33.8K)
    unsigned short* Bbuf = (unsigned short*)U;
    float* preL = (float*)(U + 16384);
    float* ipL  = (float*)U;                  // [64][132] f32
    __shared__ float basisL[640];
    __shared__ int pmL[64], sIL[64], sJL[64];
    __shared__ float fcL[64], d3L[64][3], t3L[64][3], tbL[64];

    const int t = threadIdx.x;
    const int P0 = blockIdx.x * 64;
    const int isf32 = *flagp;
    const int lane = t & 63;
    const int w = t >> 6;
    const int lc = lane & 15;
    const int quad = lane >> 4;

    if (t < 64) pmL[t] = perm[P0 + t];
    __syncthreads();
    if (t < 64) {
        const int p = pmL[t];
        int2 ij = ((const int2*)ind2)[p];
        sIL[t] = ij.x; sJL[t] = ij.y;
        fcL[t] = ldf(fc, p, isf32);
        d3L[t][0] = ldf(d3, 3 * p + 0, isf32);
        d3L[t][1] = ldf(d3, 3 * p + 1, isf32);
        d3L[t][2] = ldf(d3, 3 * p + 2, isf32);
    }
    for (int e = t; e < 640; e += 256) {
        const int m = e / 10, b = e % 10;
        basisL[e] = ldf(basis, pmL[m] * 10 + b, isf32);
    }
    __syncthreads();

    // A-frags: row m = lc (slot w*16+lc), k = s*32 + quad*8 + j
    bf16x8 ah[4], al[4];
    {
        const int ia = sIL[w * 16 + lc];
        const int ja = sJL[w * 16 + lc];
        #pragma unroll
        for (int s = 0; s < 4; s++) {
            const int atom = (s < 2) ? ia : ja;
            const int off = atom * 64 + (s & 1) * 32 + quad * 8;
            ah[s] = *(const bf16x8*)(p1h + off);
            al[s] = *(const bf16x8*)(p1l + off);
        }
    }

    // GEMM1: acc = Xh*Wh + Xl*Wh + Xh*Wl
    float sr[4][4];
    #pragma unroll
    for (int r = 0; r < 4; r++)
        #pragma unroll
        for (int ph = 0; ph < 4; ph++) sr[r][ph] = 0.f;

    for (int cc = 0; cc < 10; cc++) {
        f32x4 acc[4];
        #pragma unroll
        for (int tt = 0; tt < 4; tt++) acc[tt] = (f32x4){0.f, 0.f, 0.f, 0.f};

        __syncthreads();
        {
            const uint4* gsrc = (const uint4*)(piWBh + cc * 8192);
            uint4* ldst = (uint4*)Bbuf;
            #pragma unroll
            for (int r = 0; r < 4; r++) ldst[r * 256 + t] = gsrc[r * 256 + t];
        }
        __syncthreads();
        #pragma unroll
        for (int tt = 0; tt < 4; tt++) {
            #pragma unroll
            for (int s = 0; s < 4; s++) {
                bf16x8 bfr = *(const bf16x8*)&Bbuf[((tt * 4 + s) * 64 + lane) * 8];
                acc[tt] = __builtin_amdgcn_mfma_f32_16x16x32_bf16(ah[s], bfr, acc[tt], 0, 0, 0);
                acc[tt] = __builtin_amdgcn_mfma_f32_16x16x32_bf16(al[s], bfr, acc[tt], 0, 0, 0);
            }
        }
        __syncthreads();
        {
            const uint4* gsrc = (const uint4*)(piWBl + cc * 8192);
            uint4* ldst = (uint4*)Bbuf;
            #pragma unroll
            for (int r = 0; r < 4; r++) ldst[r * 256 + t] = gsrc[r * 256 + t];
        }
        __syncthreads();
        #pragma unroll
        for (int tt = 0; tt < 4; tt++) {
            #pragma unroll
            for (int s = 0; s < 4; s++) {
                bf16x8 bfr = *(const bf16x8*)&Bbuf[((tt * 4 + s) * 64 + lane) * 8];
                acc[tt] = __builtin_amdgcn_mfma_f32_16x16x32_bf16(ah[s], bfr, acc[tt], 0, 0, 0);
            }
            const int c = tt * 16 + lc;
            const float bias = wbuf[W_PIB + c * 10 + cc];
            #pragma unroll
            for (int r = 0; r < 4; r++) {
                const int m = w * 16 + quad * 4 + r;
                const float h = tanh_fast(acc[tt][r] + bias);
                sr[r][tt] += h * basisL[m * 10 + cc];
            }
        }
    }

    // pre -> preL (Bbuf dead after GEMM1)
    __syncthreads();
    #pragma unroll
    for (int r = 0; r < 4; r++)
        #pragma unroll
        for (int ph = 0; ph < 4; ph++)
            preL[(w * 16 + quad * 4 + r) * 68 + ph * 16 + lc] = sr[r][ph];
    __syncthreads();

    bf16x8 ah2[2], al2[2];
    {
        const int row = w * 16 + lc;
        #pragma unroll
        for (int s2 = 0; s2 < 2; s2++) {
            const float* pr2 = &preL[row * 68 + s2 * 32 + quad * 8];
            #pragma unroll
            for (int j = 0; j < 8; j++) {
                const float x = pr2[j];
                const short hs = f2bs(x);
                ah2[s2][j] = hs;
                al2[s2][j] = f2bs(x - bs2f((unsigned short)hs));
            }
        }
    }
    __syncthreads();   // preL reads done; U becomes ipL

    #pragma unroll
    for (int ct = 0; ct < 8; ct++) {
        f32x4 acc = {0.f, 0.f, 0.f, 0.f};
        #pragma unroll
        for (int s2 = 0; s2 < 2; s2++) {
            bf16x8 bh = *(const bf16x8*)&iiWh[((ct * 2 + s2) * 64 + lane) * 8];
            bf16x8 bl = *(const bf16x8*)&iiWl[((ct * 2 + s2) * 64 + lane) * 8];
            acc = __builtin_amdgcn_mfma_f32_16x16x32_bf16(ah2[s2], bh, acc, 0, 0, 0);
            acc = __builtin_amdgcn_mfma_f32_16x16x32_bf16(al2[s2], bh, acc, 0, 0, 0);
            acc = __builtin_amdgcn_mfma_f32_16x16x32_bf16(ah2[s2], bl, acc, 0, 0, 0);
        }
        const int ch = ct * 16 + lc;
        #pragma unroll
        for (int r = 0; r < 4; r++) {
            const int m = w * 16 + quad * 4 + r;
            ipL[m * 132 + ch] = tanh_fast(acc[r]);
        }
    }
    __syncthreads();   // all ip values staged

    // geometry (t<64), then phase A on all threads
    if (t < 64) {
        const int m = t;
        const int ia = sIL[m];
        const float vi0 = vglob[ia * 3 + 0], vi1 = vglob[ia * 3 + 1], vi2 = vglob[ia * 3 + 2];
        const float d0 = d3L[m][0], d1 = d3L[m][1], d2 = d3L[m][2];
        const float proj = vi0 * d0 + vi1 * d1 + vi2 * d2;
        const float w0 = vi0 - proj * d0, w1 = vi1 - proj * d1, w2v = vi2 - proj * d2;
        const float w2 = w0 * w0 + w1 * w1 + w2v * w2v;
        const float g = w2 / (w2 + 1e-4f);
        const float rs = rsqrtf(w2 + 1e-6f);
        t3L[m][0] = w0 * rs * g; t3L[m][1] = w1 * rs * g; t3L[m][2] = w2v * rs * g;
        const float f = fcL[m];
        tbL[m] = g * f * f;
    }

    // phase A: segmented sum of ip -> p1scat. ch = t&127, half = t>>7.
    {
        const int ch = t & 127;
        const int m0 = (t >> 7) * 32;
        int cur = sIL[m0];
        float acc = 0.f;
        #pragma unroll 4
        for (int m = m0; m < m0 + 32; m++) {
            const int ia = sIL[m];
            if (ia != cur) {
                atomicAdd(&p1scat[(size_t)cur * 128 + ch], acc);
                acc = 0.f; cur = ia;
            }
            acc += ipL[m * 132 + ch];
        }
        atomicAdd(&p1scat[(size_t)cur * 128 + ch], acc);
    }
    __syncthreads();   // geometry (t3L/tbL) complete before phase B

    // phase B: segmented sum of ix -> p3acc. t<192: x = t>>6, c = t&63.
    if (t < 192) {
        const int x = t >> 6, c = t & 63;
        int cur = sIL[0];
        float acc = 0.f;
        #pragma unroll 4
        for (int m = 0; m < 64; m++) {
            const int ia = sIL[m];
            if (ia != cur) {
                atomicAdd(&p3acc[(size_t)cur * 192 + x * 64 + c], acc);
                acc = 0.f; cur = ia;
            }
            const float bv = ipL[m * 132 + 64 + c];
            const float p3v = ldf(p3, sJL[m] * 192 + x * 64 + c, isf32);
            acc += p3v * bv + d3L[m][x] * bv + t3L[m][x] * (bv * tbL[m]);
        }
        atomicAdd(&p3acc[(size_t)cur * 192 + x * 64 + c], acc);
    }
}

// ---------------- per-atom epilogue ----------------
__global__ __launch_bounds__(256) void k_final(
    const float* __restrict__ p1scat, const float* __restrict__ p3acc,
    const float* __restrict__ wbuf, const int* __restrict__ flagp,
    void* __restrict__ out)
{
    const float* ppW1 = wbuf + W_PPOSTW1;
    const float* ppW2 = wbuf + W_PPOSTW2;
    const float* eqW  = wbuf + W_EQW;
    const float* q1W  = wbuf + W_Q1W;
    const float* q1b  = wbuf + W_Q1B;
    const float* q2W  = wbuf + W_Q2W;
    const float* q2b  = wbuf + W_Q2B;
    const int isf32 = *flagp;

    __shared__ float s1[4][128];
    __shared__ float hA[4][64];
    __shared__ float cat[4][128];
    __shared__ float p3a[4][192];
    const int t = threadIdx.x;
    const int slot = t >> 6, c = t & 63;
    const int atom = blockIdx.x * 4 + slot;

    s1[slot][c]        = p1scat[atom * 128 + c];
    s1[slot][64 + c]   = p1scat[atom * 128 + 64 + c];
    p3a[slot][c]       = p3acc[atom * 192 + c];
    p3a[slot][64 + c]  = p3acc[atom * 192 + 64 + c];
    p3a[slot][128 + c] = p3acc[atom * 192 + 128 + c];
    __syncthreads();

    float acc = 0.f;
    for (int k = 0; k < 128; k++) acc += s1[slot][k] * ppW1[k * 64 + c];
    hA[slot][c] = tanh_fast(acc);
    __syncthreads();
    acc = 0.f;
    for (int k = 0; k < 64; k++) acc += hA[slot][k] * ppW2[k * 64 + c];
    cat[slot][c] = tanh_fast(acc);

    float pn[3];
    float dot = 0.f;
    #pragma unroll
    for (int x = 0; x < 3; x++) {
        float a = 0.f;
        for (int k = 0; k < 64; k++) a += p3a[slot][x * 64 + k] * eqW[k * 64 + c];
        pn[x] = a;
        dot += a * a;
    }
    cat[slot][64 + c] = dot;
    __syncthreads();

    acc = q1b[c];
    for (int k = 0; k < 128; k++) acc += cat[slot][k] * q1W[k * 64 + c];
    __syncthreads();
    hA[slot][c] = tanh_fast(acc);
    __syncthreads();

    float g1acc = q2b[c], g3acc = q2b[c + 64];
    for (int k = 0; k < 64; k++) {
        const float hv = hA[slot][k];
        g1acc += hv * q2W[k * 128 + c];
        g3acc += hv * q2W[k * 128 + c + 64];
    }
    const float g1 = tanh_fast(g1acc);
    const float g3 = tanh_fast(g3acc);
    if (isf32) {
        float* p1o = (float*)out;
        float* p3o = p1o + 640000;
        p1o[atom * 64 + c] = g1;
        #pragma unroll
        for (int x = 0; x < 3; x++) p3o[atom * 192 + x * 64 + c] = pn[x] * g3;
    } else {
        __hip_bfloat16* p1o = (__hip_bfloat16*)out;
        __hip_bfloat16* p3o = p1o + 640000;
        p1o[atom * 64 + c] = __float2bfloat16(g1);
        #pragma unroll
        for (int x = 0; x < 3; x++) p3o[atom * 192 + x * 64 + c] = __float2bfloat16(pn[x] * g3);
    }
}

extern "C" void kernel_launch(void* const* d_in, const int* in_sizes, int n_in,
                              void* d_out, int out_size, void* d_ws, size_t ws_size,
                              hipStream_t stream)
{
    const int* ind2 = (const int*)d_in[0];
    const void* p1    = d_in[1];
    const void* p3    = d_in[2];
    const void* basis = d_in[3];
    const void* d3    = d_in[4];
    const void* fc    = d_in[5];

    char* W = (char*)d_ws;
    float* wbuf  = (float*)(W + 0);                       // 528128 B
    short* piWBh = (short*)(W + 528128);                  // 163840 B
    short* piWBl = (short*)(W + 691968);                  // 163840 B
    short* iiWh  = (short*)(W + 855808);                  // 16384 B
    short* iiWl  = (short*)(W + 872192);                  // 16384 B
    unsigned short* p1h = (unsigned short*)(W + 888576);  // 1280000 B
    unsigned short* p1l = (unsigned short*)(W + 2168576); // 1280000 B
    int*   flag  = (int*)(W + 3448576);                   // pad -> 3448640
    int*   cnt   = (int*)(W + 3448640);                   // 40000 B
    int*   offs  = (int*)(W + 3488640);                   // 40016 B -> pad 3528704
    int*   cur   = (int*)(W + 3528704);                   // 40000 B
    int*   perm  = (int*)(W + 3568704);                   // 1280000 B
    float* v      = (float*)(W + 4848704);                // 120000 B
    float* p1scat = (float*)(W + 4968704);                // 5120000 B
    float* p3acc  = (float*)(W + 10088704);               // 7680000 B -> ends 17768704

    hipMemsetAsync(cnt, 0, 40000, stream);
    hipMemsetAsync(v, 0, 120000 + 5120000 + 7680000, stream);

    k_probe<<<1, 64, 0, stream>>>(d3, flag);
    k_convert<<<516, 256, 0, stream>>>(
        d_in[6], d_in[7], d_in[8], d_in[9], d_in[10], d_in[11], d_in[12],
        d_in[13], d_in[14], d_in[15], d_in[16], d_in[17], d_in[18], d_in[19],
        wbuf, flag);
    k_pack<<<352, 256, 0, stream>>>(wbuf, piWBh, piWBl, iiWh, iiWl);
    k_p1in<<<2500, 256, 0, stream>>>(p1, wbuf, flag, p1h, p1l);

    k_hist<<<1250, 256, 0, stream>>>(ind2, cnt);
    k_scan<<<1, 256, 0, stream>>>(cnt, offs);
    k_cpcur<<<40, 256, 0, stream>>>(offs, cur);
    k_scatter<<<1250, 256, 0, stream>>>(ind2, cur, perm);
    k_vscat<<<1250, 256, 0, stream>>>(ind2, d3, fc, flag, perm, v);

    k_pairs<<<5000, 256, 0, stream>>>(ind2, basis, d3, fc, p3,
                                      wbuf, piWBh, piWBl, iiWh, iiWl,
                                      p1h, p1l, flag, v, perm,
                                      p1scat, p3acc);
    k_final<<<2500, 256, 0, stream>>>(p1scat, p3acc, wbuf, flag, d_out);
}

// Round 10
// 557.828 us; speedup vs baseline: 1.0019x; 1.0019x over previous
//
#include <hip/hip_runtime.h>
#include <hip/hip_bf16.h>
#include <hip/hip_fp16.h>

#define N_ATOMS 10000
#define N_PAIRS 320000
#define C_ 64
#define NB_ 10

typedef short bf16x8 __attribute__((ext_vector_type(8)));
typedef float f32x4 __attribute__((ext_vector_type(4)));

__device__ __forceinline__ float bf2f(__hip_bfloat16 x) { return __bfloat162float(x); }
__device__ __forceinline__ float ldf(const void* p, int i, int isf32) {
    return isf32 ? ((const float*)p)[i] : bf2f(((const __hip_bfloat16*)p)[i]);
}
__device__ __forceinline__ short f2bs(float x) {
    __hip_bfloat16 h = __float2bfloat16(x);
    return *reinterpret_cast<short*>(&h);
}
__device__ __forceinline__ float bs2f(unsigned short s) {
    return __uint_as_float(((unsigned)s) << 16);
}
// fast tanh: 1 - 2/(exp(2x)+1). err ~1e-6, saturates correctly at +-inf.
__device__ __forceinline__ float tanh_fast(float x) {
    const float e = __expf(2.0f * x);
    return 1.0f - 2.0f * __builtin_amdgcn_rcpf(e + 1.0f);
}

// wbuf f32 offsets
#define W_PPREW1 0
#define W_PPREB1 4096
#define W_PPREW2 4160
#define W_PPREB2 8256
#define W_PIW    8320
#define W_PIB    90240
#define W_IIW    90880
#define W_PPOSTW1 99072
#define W_PPOSTW2 107264
#define W_EQW    111360
#define W_Q1W    115456
#define W_Q1B    123648
#define W_Q2W    123712
#define W_Q2B    131904
#define W_TOTAL  132032

// ---------------- probe dtype ----------------
__global__ void k_probe(const void* __restrict__ d3, int* __restrict__ flag)
{
    if (threadIdx.x == 0 && blockIdx.x == 0) {
        float sf = 0.f, sb = 0.f;
        const float* f = (const float*)d3;
        const __hip_bfloat16* b = (const __hip_bfloat16*)d3;
        for (int r = 0; r < 4; r++) {
            float x = f[r*3], y = f[r*3+1], z = f[r*3+2];
            float n = x*x + y*y + z*z;
            sf += isfinite(n) ? fabsf(n - 1.f) : 1e30f;
            float xb = bf2f(b[r*3]), yb = bf2f(b[r*3+1]), zb = bf2f(b[r*3+2]);
            float nb = xb*xb + yb*yb + zb*zb;
            sb += isfinite(nb) ? fabsf(nb - 1.f) : 1e30f;
        }
        *flag = (sf < sb) ? 1 : 0;
    }
}

// ---------------- gather all weights into f32 wbuf ----------------
__global__ __launch_bounds__(256) void k_convert(
    const void* s0, const void* s1, const void* s2, const void* s3,
    const void* s4, const void* s5, const void* s6, const void* s7,
    const void* s8, const void* s9, const void* s10, const void* s11,
    const void* s12, const void* s13,
    float* __restrict__ wbuf, const int* __restrict__ flagp)
{
    const int idx = blockIdx.x * 256 + threadIdx.x;
    if (idx >= W_TOTAL) return;
    const int isf32 = *flagp;
    const int offs[15] = {W_PPREW1, W_PPREB1, W_PPREW2, W_PPREB2, W_PIW, W_PIB,
                          W_IIW, W_PPOSTW1, W_PPOSTW2, W_EQW, W_Q1W, W_Q1B,
                          W_Q2W, W_Q2B, W_TOTAL};
    const void* srcs[14] = {s0,s1,s2,s3,s4,s5,s6,s7,s8,s9,s10,s11,s12,s13};
    int t = 0;
    while (idx >= offs[t + 1]) t++;
    wbuf[idx] = ldf(srcs[t], idx - offs[t], isf32);
}

// ---------------- p3 -> fp16 (3.84 MB, fits one XCD L2; 11-bit mantissa).
// bf16 (8-bit mantissa) FAILED here twice: the p3acc accumulation is coherent,
// so relative quantization error passes straight to the ~454-magnitude output
// (0.89 = 1 bf16 ulp). fp16's 2^-12 rel err -> ~0.11 on output. ----------------
__global__ __launch_bounds__(256) void k_p3cvt(
    const void* __restrict__ p3, const int* __restrict__ flagp,
    __half* __restrict__ p3h)
{
    const int idx = blockIdx.x * 256 + threadIdx.x;
    if (idx >= N_ATOMS * 192) return;
    const int isf32 = *flagp;
    p3h[idx] = __float2half(ldf(p3, idx, isf32));
}

// ---------------- pack MFMA B-operand buffers (hi + lo split) ----------------
__global__ __launch_bounds__(256) void k_pack(
    const float* __restrict__ wbuf,
    short* __restrict__ piWBh, short* __restrict__ piWBl,
    short* __restrict__ iiWh, short* __restrict__ iiWl)
{
    int idx = blockIdx.x * 256 + threadIdx.x;
    if (idx < 81920) {
        const int j = idx & 7, lane = (idx >> 3) & 63, s = (idx >> 9) & 3, T = idx >> 11;
        const int k = s * 32 + (lane >> 4) * 8 + j;
        const int colp = T * 16 + (lane & 15);
        const int b = colp >> 6, c = colp & 63;
        const float v = wbuf[W_PIW + k * 640 + c * 10 + b];
        const short hs = f2bs(v);
        piWBh[idx] = hs;
        piWBl[idx] = f2bs(v - bs2f((unsigned short)hs));
        return;
    }
    idx -= 81920;
    if (idx < 8192) {
        const int j = idx & 7, lane = (idx >> 3) & 63, s2 = (idx >> 9) & 1, ct = idx >> 10;
        const int k = s2 * 32 + (lane >> 4) * 8 + j;
        const int col = ct * 16 + (lane & 15);
        const float wv = wbuf[W_IIW + k * 128 + col];
        const short hs = f2bs(wv);
        iiWh[idx] = hs;
        iiWl[idx] = f2bs(wv - bs2f((unsigned short)hs));
    }
}

// ---------------- p1_in split into hi/lo bf16 ----------------
__global__ __launch_bounds__(256) void k_p1in(
    const void* __restrict__ p1, const float* __restrict__ wbuf,
    const int* __restrict__ flagp,
    unsigned short* __restrict__ p1h, unsigned short* __restrict__ p1l)
{
    const float* W1 = wbuf + W_PPREW1;
    const float* b1 = wbuf + W_PPREB1;
    const float* W2 = wbuf + W_PPREW2;
    const float* b2 = wbuf + W_PPREB2;
    const int isf32 = *flagp;
    __shared__ float x[4][C_];
    __shared__ float h[4][C_];
    const int t = threadIdx.x;
    const int slot = t >> 6, c = t & 63;
    const int atom = blockIdx.x * 4 + slot;
    x[slot][c] = ldf(p1, atom * C_ + c, isf32);
    __syncthreads();
    float acc = b1[c];
    for (int k = 0; k < C_; k++) acc += x[slot][k] * W1[k * C_ + c];
    h[slot][c] = tanh_fast(acc);
    __syncthreads();
    acc = b2[c];
    for (int k = 0; k < C_; k++) acc += h[slot][k] * W2[k * C_ + c];
    const float f = tanh_fast(acc);
    const short hs = f2bs(f);
    p1h[atom * C_ + c] = (unsigned short)hs;
    p1l[atom * C_ + c] = (unsigned short)f2bs(f - bs2f((unsigned short)hs));
}

// ---------------- sort machinery ----------------
__global__ __launch_bounds__(256) void k_hist(const int* __restrict__ ind2, int* __restrict__ cnt)
{
    const int p = blockIdx.x * 256 + threadIdx.x;
    if (p < N_PAIRS) atomicAdd(&cnt[ind2[2 * p]], 1);
}
__global__ __launch_bounds__(256) void k_scan(const int* __restrict__ cnt, int* __restrict__ offs)
{
    __shared__ int part[256];
    __shared__ int base[257];
    const int t = threadIdx.x;
    const int lo = t * 40, hi = (lo + 40 < N_ATOMS) ? lo + 40 : N_ATOMS;
    int s = 0;
    for (int b = lo; b < hi; b++) s += cnt[b];
    part[t] = s;
    __syncthreads();
    if (t == 0) {
        int run = 0;
        for (int i = 0; i < 256; i++) { base[i] = run; run += part[i]; }
        base[256] = run;
    }
    __syncthreads();
    int run = base[t];
    for (int b = lo; b < hi; b++) { offs[b] = run; run += cnt[b]; }
    if (t == 0) offs[N_ATOMS] = base[256];
}
__global__ __launch_bounds__(256) void k_cpcur(const int* __restrict__ offs, int* __restrict__ cur)
{
    const int i = blockIdx.x * 256 + threadIdx.x;
    if (i < N_ATOMS) cur[i] = offs[i];
}
__global__ __launch_bounds__(256) void k_scatter(const int* __restrict__ ind2,
                                                 int* __restrict__ cur, int* __restrict__ perm)
{
    const int p = blockIdx.x * 256 + threadIdx.x;
    if (p >= N_PAIRS) return;
    const int pos = atomicAdd(&cur[ind2[2 * p]], 1);
    perm[pos] = p;
}

// ---------------- v = segment_sum(d3*fc) via sorted head-scan ----------------
__global__ __launch_bounds__(256) void k_vscat(
    const int* __restrict__ ind2, const void* __restrict__ d3,
    const void* __restrict__ fc, const int* __restrict__ flagp,
    const int* __restrict__ perm, float* __restrict__ v)
{
    __shared__ int iA[256];
    __shared__ float sx[256], sy[256], sz[256];
    const int t = threadIdx.x;
    const int q = blockIdx.x * 256 + t;
    const int isf32 = *flagp;
    const int p = perm[q];
    const int ia = ind2[2 * p];
    const float f = ldf(fc, p, isf32);
    iA[t] = ia;
    sx[t] = ldf(d3, 3 * p + 0, isf32) * f;
    sy[t] = ldf(d3, 3 * p + 1, isf32) * f;
    sz[t] = ldf(d3, 3 * p + 2, isf32) * f;
    __syncthreads();
    const bool head = (t == 0) || (iA[t - 1] != ia);
    if (head) {
        float ax = sx[t], ay = sy[t], az = sz[t];
        int m = t + 1;
        while (m < 256 && iA[m] == ia) { ax += sx[m]; ay += sy[m]; az += sz[m]; m++; }
        atomicAdd(&v[ia * 3 + 0], ax);
        atomicAdd(&v[ia * 3 + 1], ay);
        atomicAdd(&v[ia * 3 + 2], az);
    }
}

// ---------------- main per-pair MFMA kernel, sorted order, segmented scatter ----------------
__global__ __launch_bounds__(256) void k_pairs(
    const int* __restrict__ ind2, const void* __restrict__ basis,
    const void* __restrict__ d3, const void* __restrict__ fc,
    const __half* __restrict__ p3h,
    const float* __restrict__ wbuf,
    const short* __restrict__ piWBh, const short* __restrict__ piWBl,
    const short* __restrict__ iiWh, const short* __restrict__ iiWl,
    const unsigned short* __restrict__ p1h, const unsigned short* __restrict__ p1l,
    const int* __restrict__ flagp, const float* __restrict__ vglob,
    const int* __restrict__ perm,
    float* __restrict__ p1scat, float* __restrict__ p3acc)
{
    __shared__ __align__(16) char U[33792];   // Bbuf(16K)+preL(17.4K) -> ipL(33.8K)
    unsigned short* Bbuf = (unsigned short*)U;
    float* preL = (float*)(U + 16384);
    float* ipL  = (float*)U;                  // [64][132] f32
    __shared__ float basisL[640];
    __shared__ int pmL[64], sIL[64], sJL[64];
    __shared__ float fcL[64], d3L[64][3], t3L[64][3], tbL[64];

    const int t = threadIdx.x;
    const int P0 = blockIdx.x * 64;
    const int isf32 = *flagp;
    const int lane = t & 63;
    const int w = t >> 6;
    const int lc = lane & 15;
    const int quad = lane >> 4;

    if (t < 64) pmL[t] = perm[P0 + t];
    __syncthreads();
    if (t < 64) {
        const int p = pmL[t];
        int2 ij = ((const int2*)ind2)[p];
        sIL[t] = ij.x; sJL[t] = ij.y;
        fcL[t] = ldf(fc, p, isf32);
        d3L[t][0] = ldf(d3, 3 * p + 0, isf32);
        d3L[t][1] = ldf(d3, 3 * p + 1, isf32);
        d3L[t][2] = ldf(d3, 3 * p + 2, isf32);
    }
    for (int e = t; e < 640; e += 256) {
        const int m = e / 10, b = e % 10;
        basisL[e] = ldf(basis, pmL[m] * 10 + b, isf32);
    }
    __syncthreads();

    // A-frags: row m = lc (slot w*16+lc), k = s*32 + quad*8 + j
    bf16x8 ah[4], al[4];
    {
        const int ia = sIL[w * 16 + lc];
        const int ja = sJL[w * 16 + lc];
        #pragma unroll
        for (int s = 0; s < 4; s++) {
            const int atom = (s < 2) ? ia : ja;
            const int off = atom * 64 + (s & 1) * 32 + quad * 8;
            ah[s] = *(const bf16x8*)(p1h + off);
            al[s] = *(const bf16x8*)(p1l + off);
        }
    }

    // GEMM1: acc = Xh*Wh + Xl*Wh + Xh*Wl
    float sr[4][4];
    #pragma unroll
    for (int r = 0; r < 4; r++)
        #pragma unroll
        for (int ph = 0; ph < 4; ph++) sr[r][ph] = 0.f;

    for (int cc = 0; cc < 10; cc++) {
        f32x4 acc[4];
        #pragma unroll
        for (int tt = 0; tt < 4; tt++) acc[tt] = (f32x4){0.f, 0.f, 0.f, 0.f};

        __syncthreads();
        {
            const uint4* gsrc = (const uint4*)(piWBh + cc * 8192);
            uint4* ldst = (uint4*)Bbuf;
            #pragma unroll
            for (int r = 0; r < 4; r++) ldst[r * 256 + t] = gsrc[r * 256 + t];
        }
        __syncthreads();
        #pragma unroll
        for (int tt = 0; tt < 4; tt++) {
            #pragma unroll
            for (int s = 0; s < 4; s++) {
                bf16x8 bfr = *(const bf16x8*)&Bbuf[((tt * 4 + s) * 64 + lane) * 8];
                acc[tt] = __builtin_amdgcn_mfma_f32_16x16x32_bf16(ah[s], bfr, acc[tt], 0, 0, 0);
                acc[tt] = __builtin_amdgcn_mfma_f32_16x16x32_bf16(al[s], bfr, acc[tt], 0, 0, 0);
            }
        }
        __syncthreads();
        {
            const uint4* gsrc = (const uint4*)(piWBl + cc * 8192);
            uint4* ldst = (uint4*)Bbuf;
            #pragma unroll
            for (int r = 0; r < 4; r++) ldst[r * 256 + t] = gsrc[r * 256 + t];
        }
        __syncthreads();
        #pragma unroll
        for (int tt = 0; tt < 4; tt++) {
            #pragma unroll
            for (int s = 0; s < 4; s++) {
                bf16x8 bfr = *(const bf16x8*)&Bbuf[((tt * 4 + s) * 64 + lane) * 8];
                acc[tt] = __builtin_amdgcn_mfma_f32_16x16x32_bf16(ah[s], bfr, acc[tt], 0, 0, 0);
            }
            const int c = tt * 16 + lc;
            const float bias = wbuf[W_PIB + c * 10 + cc];
            #pragma unroll
            for (int r = 0; r < 4; r++) {
                const int m = w * 16 + quad * 4 + r;
                const float h = tanh_fast(acc[tt][r] + bias);
                sr[r][tt] += h * basisL[m * 10 + cc];
            }
        }
    }

    // pre -> preL (Bbuf dead after GEMM1)
    __syncthreads();
    #pragma unroll
    for (int r = 0; r < 4; r++)
        #pragma unroll
        for (int ph = 0; ph < 4; ph++)
            preL[(w * 16 + quad * 4 + r) * 68 + ph * 16 + lc] = sr[r][ph];
    __syncthreads();

    bf16x8 ah2[2], al2[2];
    {
        const int row = w * 16 + lc;
        #pragma unroll
        for (int s2 = 0; s2 < 2; s2++) {
            const float* pr2 = &preL[row * 68 + s2 * 32 + quad * 8];
            #pragma unroll
            for (int j = 0; j < 8; j++) {
                const float x = pr2[j];
                const short hs = f2bs(x);
                ah2[s2][j] = hs;
                al2[s2][j] = f2bs(x - bs2f((unsigned short)hs));
            }
        }
    }
    __syncthreads();   // preL reads done; U becomes ipL

    #pragma unroll
    for (int ct = 0; ct < 8; ct++) {
        f32x4 acc = {0.f, 0.f, 0.f, 0.f};
        #pragma unroll
        for (int s2 = 0; s2 < 2; s2++) {
            bf16x8 bh = *(const bf16x8*)&iiWh[((ct * 2 + s2) * 64 + lane) * 8];
            bf16x8 bl = *(const bf16x8*)&iiWl[((ct * 2 + s2) * 64 + lane) * 8];
            acc = __builtin_amdgcn_mfma_f32_16x16x32_bf16(ah2[s2], bh, acc, 0, 0, 0);
            acc = __builtin_amdgcn_mfma_f32_16x16x32_bf16(al2[s2], bh, acc, 0, 0, 0);
            acc = __builtin_amdgcn_mfma_f32_16x16x32_bf16(ah2[s2], bl, acc, 0, 0, 0);
        }
        const int ch = ct * 16 + lc;
        #pragma unroll
        for (int r = 0; r < 4; r++) {
            const int m = w * 16 + quad * 4 + r;
            ipL[m * 132 + ch] = tanh_fast(acc[r]);
        }
    }
    __syncthreads();   // all ip values staged

    // geometry (t<64), then phase A on all threads
    if (t < 64) {
        const int m = t;
        const int ia = sIL[m];
        const float vi0 = vglob[ia * 3 + 0], vi1 = vglob[ia * 3 + 1], vi2 = vglob[ia * 3 + 2];
        const float d0 = d3L[m][0], d1 = d3L[m][1], d2 = d3L[m][2];
        const float proj = vi0 * d0 + vi1 * d1 + vi2 * d2;
        const float w0 = vi0 - proj * d0, w1 = vi1 - proj * d1, w2v = vi2 - proj * d2;
        const float w2 = w0 * w0 + w1 * w1 + w2v * w2v;
        const float g = w2 / (w2 + 1e-4f);
        const float rs = rsqrtf(w2 + 1e-6f);
        t3L[m][0] = w0 * rs * g; t3L[m][1] = w1 * rs * g; t3L[m][2] = w2v * rs * g;
        const float f = fcL[m];
        tbL[m] = g * f * f;
    }

    // phase A: segmented sum of ip -> p1scat. ch = t&127, half = t>>7.
    {
        const int ch = t & 127;
        const int m0 = (t >> 7) * 32;
        int cur = sIL[m0];
        float acc = 0.f;
        #pragma unroll 4
        for (int m = m0; m < m0 + 32; m++) {
            const int ia = sIL[m];
            if (ia != cur) {
                atomicAdd(&p1scat[(size_t)cur * 128 + ch], acc);
                acc = 0.f; cur = ia;
            }
            acc += ipL[m * 132 + ch];
        }
        atomicAdd(&p1scat[(size_t)cur * 128 + ch], acc);
    }
    __syncthreads();   // geometry (t3L/tbL) complete before phase B

    // phase B: segmented sum of ix -> p3acc; p3 gathered as fp16 (L2-resident)
    if (t < 192) {
        const int x = t >> 6, c = t & 63;
        int cur = sIL[0];
        float acc = 0.f;
        #pragma unroll 4
        for (int m = 0; m < 64; m++) {
            const int ia = sIL[m];
            if (ia != cur) {
                atomicAdd(&p3acc[(size_t)cur * 192 + x * 64 + c], acc);
                acc = 0.f; cur = ia;
            }
            const float bv = ipL[m * 132 + 64 + c];
            const float p3v = __half2float(p3h[sJL[m] * 192 + x * 64 + c]);
            acc += p3v * bv + d3L[m][x] * bv + t3L[m][x] * (bv * tbL[m]);
        }
        atomicAdd(&p3acc[(size_t)cur * 192 + x * 64 + c], acc);
    }
}

// ---------------- per-atom epilogue ----------------
__global__ __launch_bounds__(256) void k_final(
    const float* __restrict__ p1scat, const float* __restrict__ p3acc,
    const float* __restrict__ wbuf, const int* __restrict__ flagp,
    void* __restrict__ out)
{
    const float* ppW1 = wbuf + W_PPOSTW1;
    const float* ppW2 = wbuf + W_PPOSTW2;
    const float* eqW  = wbuf + W_EQW;
    const float* q1W  = wbuf + W_Q1W;
    const float* q1b  = wbuf + W_Q1B;
    const float* q2W  = wbuf + W_Q2W;
    const float* q2b  = wbuf + W_Q2B;
    const int isf32 = *flagp;

    __shared__ float s1[4][128];
    __shared__ float hA[4][64];
    __shared__ float cat[4][128];
    __shared__ float p3a[4][192];
    const int t = threadIdx.x;
    const int slot = t >> 6, c = t & 63;
    const int atom = blockIdx.x * 4 + slot;

    s1[slot][c]        = p1scat[atom * 128 + c];
    s1[slot][64 + c]   = p1scat[atom * 128 + 64 + c];
    p3a[slot][c]       = p3acc[atom * 192 + c];
    p3a[slot][64 + c]  = p3acc[atom * 192 + 64 + c];
    p3a[slot][128 + c] = p3acc[atom * 192 + 128 + c];
    __syncthreads();

    float acc = 0.f;
    for (int k = 0; k < 128; k++) acc += s1[slot][k] * ppW1[k * 64 + c];
    hA[slot][c] = tanh_fast(acc);
    __syncthreads();
    acc = 0.f;
    for (int k = 0; k < 64; k++) acc += hA[slot][k] * ppW2[k * 64 + c];
    cat[slot][c] = tanh_fast(acc);

    float pn[3];
    float dot = 0.f;
    #pragma unroll
    for (int x = 0; x < 3; x++) {
        float a = 0.f;
        for (int k = 0; k < 64; k++) a += p3a[slot][x * 64 + k] * eqW[k * 64 + c];
        pn[x] = a;
        dot += a * a;
    }
    cat[slot][64 + c] = dot;
    __syncthreads();

    acc = q1b[c];
    for (int k = 0; k < 128; k++) acc += cat[slot][k] * q1W[k * 64 + c];
    __syncthreads();
    hA[slot][c] = tanh_fast(acc);
    __syncthreads();

    float g1acc = q2b[c], g3acc = q2b[c + 64];
    for (int k = 0; k < 64; k++) {
        const float hv = hA[slot][k];
        g1acc += hv * q2W[k * 128 + c];
        g3acc += hv * q2W[k * 128 + c + 64];
    }
    const float g1 = tanh_fast(g1acc);
    const float g3 = tanh_fast(g3acc);
    if (isf32) {
        float* p1o = (float*)out;
        float* p3o = p1o + 640000;
        p1o[atom * 64 + c] = g1;
        #pragma unroll
        for (int x = 0; x < 3; x++) p3o[atom * 192 + x * 64 + c] = pn[x] * g3;
    } else {
        __hip_bfloat16* p1o = (__hip_bfloat16*)out;
        __hip_bfloat16* p3o = p1o + 640000;
        p1o[atom * 64 + c] = __float2bfloat16(g1);
        #pragma unroll
        for (int x = 0; x < 3; x++) p3o[atom * 192 + x * 64 + c] = __float2bfloat16(pn[x] * g3);
    }
}

extern "C" void kernel_launch(void* const* d_in, const int* in_sizes, int n_in,
                              void* d_out, int out_size, void* d_ws, size_t ws_size,
                              hipStream_t stream)
{
    const int* ind2 = (const int*)d_in[0];
    const void* p1    = d_in[1];
    const void* p3    = d_in[2];
    const void* basis = d_in[3];
    const void* d3    = d_in[4];
    const void* fc    = d_in[5];

    char* W = (char*)d_ws;
    float* wbuf  = (float*)(W + 0);                       // 528128 B
    short* piWBh = (short*)(W + 528128);                  // 163840 B
    short* piWBl = (short*)(W + 691968);                  // 163840 B
    short* iiWh  = (short*)(W + 855808);                  // 16384 B
    short* iiWl  = (short*)(W + 872192);                  // 16384 B
    unsigned short* p1h = (unsigned short*)(W + 888576);  // 1280000 B
    unsigned short* p1l = (unsigned short*)(W + 2168576); // 1280000 B
    int*   flag  = (int*)(W + 3448576);                   // pad -> 3448640
    int*   cnt   = (int*)(W + 3448640);                   // 40000 B
    int*   offs  = (int*)(W + 3488640);                   // 40016 B -> pad 3528704
    int*   cur   = (int*)(W + 3528704);                   // 40000 B
    int*   perm  = (int*)(W + 3568704);                   // 1280000 B
    float* v      = (float*)(W + 4848704);                // 120000 B
    float* p1scat = (float*)(W + 4968704);                // 5120000 B
    float* p3acc  = (float*)(W + 10088704);               // 7680000 B
    __half* p3h = (__half*)(W + 17768704);                // 3840000 B -> ends 21608704

    hipMemsetAsync(cnt, 0, 40000, stream);
    hipMemsetAsync(v, 0, 120000 + 5120000 + 7680000, stream);

    k_probe<<<1, 64, 0, stream>>>(d3, flag);
    k_convert<<<516, 256, 0, stream>>>(
        d_in[6], d_in[7], d_in[8], d_in[9], d_in[10], d_in[11], d_in[12],
        d_in[13], d_in[14], d_in[15], d_in[16], d_in[17], d_in[18], d_in[19],
        wbuf, flag);
    k_p3cvt<<<7500, 256, 0, stream>>>(p3, flag, p3h);
    k_pack<<<352, 256, 0, stream>>>(wbuf, piWBh, piWBl, iiWh, iiWl);
    k_p1in<<<2500, 256, 0, stream>>>(p1, wbuf, flag, p1h, p1l);

    k_hist<<<1250, 256, 0, stream>>>(ind2, cnt);
    k_scan<<<1, 256, 0, stream>>>(cnt, offs);
    k_cpcur<<<40, 256, 0, stream>>>(offs, cur);
    k_scatter<<<1250, 256, 0, stream>>>(ind2, cur, perm);
    k_vscat<<<1250, 256, 0, stream>>>(ind2, d3, fc, flag, perm, v);

    k_pairs<<<5000, 256, 0, stream>>>(ind2, basis, d3, fc, p3h,
                                      wbuf, piWBh, piWBl, iiWh, iiWl,
                                      p1h, p1l, flag, v, perm,
                                      p1scat, p3acc);
    k_final<<<2500, 256, 0, stream>>>(p1scat, p3acc, wbuf, flag, d_out);
}